// Round 4
// baseline (42.970 us; speedup 1.0000x reference)
//
#include <hip/hip_runtime.h>
#include <math.h>

#define N_ATOMS 4096
#define CUTOFF2 25.0f
#define NBLK    512
#define IPB     8                    // i atoms per block
#define CHUNK   256                  // j atoms staged per chunk
#define NCHUNK  (N_ATOMS / CHUNK)    // 16
#define ROW     12                   // floats per packed row
#define LOG2E   1.4426950408889634f
#define LN2     0.6931471805599453f

__device__ __forceinline__ float pow20f(float t) {
    float t2 = t * t;
    float t4 = t2 * t2;
    float t8 = t4 * t4;
    float t16 = t8 * t8;
    return t16 * t4;
}

// packed row: [x,y,z,re_inv | c1b,la,fe,Bof | c1a,ka,A,pad]
//   c1b = beta*log2e  (exp arg = fma(-x, c1b, c1b)),  c1a likewise for alpha
//   Bof = B/fe  (phi 2nd term = Bof * f_r)
__global__ __launch_bounds__(256) void pack_kernel(
    const float* __restrict__ coords, const float* __restrict__ params,
    float* __restrict__ packed, int* __restrict__ done_ctr)
{
    if (blockIdx.x == 0 && threadIdx.x == 0) *done_ctr = 0;   // reset for fused kernel
    const int a = blockIdx.x * 256 + threadIdx.x;
    const float* p = params + 22 * a;
    const float fe = p[1];
    float4 q0 = { coords[3*a], coords[3*a+1], coords[3*a+2], __builtin_amdgcn_rcpf(p[0]) };
    float4 q1 = { p[5] * LOG2E, p[9], fe, p[7] * __builtin_amdgcn_rcpf(fe) };
    float4 q2 = { p[4] * LOG2E, p[8], p[6], 0.0f };
    float4* dst = (float4*)(packed + (size_t)ROW * a);
    dst[0] = q0; dst[1] = q1; dst[2] = q2;
}

// 512 blocks x 256 threads. Block owns 8 i-atoms (wave w -> i 2w,2w+1; 32 lanes each).
// Loops all 4096 j in 16 staged chunks; completes rho, F(rho), pair-e, block partial.
// Last-finishing block sums the 512 partials in fixed order -> out[0].
__global__ __launch_bounds__(256) void eam_fused_kernel(
    const float* __restrict__ params, const float* __restrict__ packed,
    float* __restrict__ partials, int* __restrict__ done_ctr,
    float* __restrict__ out)
{
    __shared__ float4 spp4[CHUNK * ROW / 4];     // 12 KB
    float* spp = (float*)spp4;
    __shared__ float sF[IPB];
    __shared__ float sE[4];
    __shared__ float sR[4];
    __shared__ int   sLast;

    const int tid  = threadIdx.x;
    const int il   = tid >> 5;        // 0..7
    const int lane = tid & 31;
    const int i    = blockIdx.x * IPB + il;

    // i-side folded params (broadcast loads, L1/L2-resident)
    const float4 pi0 = *(const float4*)(packed + (size_t)ROW * i);
    const float4 pi1 = *(const float4*)(packed + (size_t)ROW * i + 4);
    const float4 pi2 = *(const float4*)(packed + (size_t)ROW * i + 8);
    const float xi = pi0.x, yi = pi0.y, zi = pi0.z, re_inv_i = pi0.w;
    const float c1b_i = pi1.x, la_i = pi1.y, fe_i = pi1.z, Bof_i = pi1.w;
    const float c1a_i = pi2.x, ka_i = pi2.y, A_i = pi2.z;

    float rho = 0.0f;
    float e   = 0.0f;

    for (int c = 0; c < NCHUNK; ++c) {
        __syncthreads();
        {   // stage chunk: 768 float4 = 12 KB, coalesced
            const float4* src = (const float4*)packed + (size_t)c * (CHUNK * ROW / 4);
            spp4[tid]       = src[tid];
            spp4[tid + 256] = src[tid + 256];
            spp4[tid + 512] = src[tid + 512];
        }
        __syncthreads();

        #pragma unroll
        for (int k = 0; k < CHUNK / 32; ++k) {
            const int jj = lane + 32 * k;
            const int j  = c * CHUNK + jj;
            const float4 q0 = *(const float4*)&spp[jj * ROW];      // x,y,z,re_inv
            const float4 q1 = *(const float4*)&spp[jj * ROW + 4];  // c1b,la,fe,Bof
            const float dx = q0.x - xi;
            const float dy = q0.y - yi;
            const float dz = q0.z - zi;
            const float r2 = fmaf(dx, dx, fmaf(dy, dy, dz * dz));
            const float r  = __builtin_amdgcn_sqrtf(r2);
            const float x  = r * q0.w;
            const float ej = __builtin_amdgcn_exp2f(fmaf(-x, q1.x, q1.x));
            const float tj = x - q1.y;
            const float dj = __builtin_amdgcn_rcpf(1.0f + pow20f(tj));
            const float frj = q1.z * ej * dj;
            rho += (j == i) ? 0.0f : frj;

            if (r2 <= CUTOFF2 && i < j) {   // pair energy, each unordered pair once
                const float4 q2 = *(const float4*)&spp[jj * ROW + 8];  // c1a,ka,A,-
                const float xr  = r * re_inv_i;
                const float ei  = __builtin_amdgcn_exp2f(fmaf(-xr, c1b_i, c1b_i));
                const float di  = __builtin_amdgcn_rcpf(1.0f + pow20f(xr - la_i));
                const float fri = fe_i * ei * di;
                const float ph_i = A_i * __builtin_amdgcn_exp2f(fmaf(-xr, c1a_i, c1a_i))
                                       * __builtin_amdgcn_rcpf(1.0f + pow20f(xr - ka_i))
                                 - Bof_i * fri;
                const float ph_j = q2.z * __builtin_amdgcn_exp2f(fmaf(-x, q2.x, q2.x))
                                        * __builtin_amdgcn_rcpf(1.0f + pow20f(x - q2.y))
                                 - q1.w * frj;
                // frj/fri*ph_i + fri/frj*ph_j = (frj^2*ph_i + fri^2*ph_j)/(fri*frj)
                e += 0.5f * fmaf(frj * frj, ph_i, fri * fri * ph_j)
                          * __builtin_amdgcn_rcpf(fri * frj);
            }
        }
    }

    // rho complete for atom i: reduce across this i's 32 lanes
    #pragma unroll
    for (int off = 16; off > 0; off >>= 1) rho += __shfl_down(rho, off, 32);
    // pair-e: reduce across full wave
    #pragma unroll
    for (int off = 32; off > 0; off >>= 1) e += __shfl_down(e, off, 64);

    if (lane == 0) {   // embedding F(rho), 8 lanes per block active
        const float* p = params + 22 * i;
        float F;
        if (rho < p[20]) {
            const float xn = rho / p[20] - 1.0f;
            F = p[10] + xn * (p[11] + xn * (p[12] + xn * p[13]));
        } else if (rho < p[21]) {
            const float xe = rho / p[2] - 1.0f;
            F = p[14] + xe * (p[15] + xe * (p[16] + xe * p[17]));
        } else {
            const float l2 = __builtin_amdgcn_logf(rho / p[3]);   // log2
            const float t  = __builtin_amdgcn_exp2f(p[18] * l2);
            const float lt = p[18] * l2 * LN2;                    // ln(t)
            F = p[19] * (1.0f - lt) * t;
        }
        sF[il] = F;
    }
    if ((tid & 63) == 0) sE[tid >> 6] = e;
    __syncthreads();

    if (tid == 0) {
        float part = sE[0] + sE[1] + sE[2] + sE[3];
        #pragma unroll
        for (int k = 0; k < IPB; ++k) part += sF[k];
        partials[blockIdx.x] = part;
        // release: makes the partial visible device-wide before the count
        int prev = __hip_atomic_fetch_add(done_ctr, 1, __ATOMIC_ACQ_REL,
                                          __HIP_MEMORY_SCOPE_AGENT);
        sLast = (prev == NBLK - 1);
    }
    __syncthreads();

    if (sLast) {   // this block arrived last: all partials visible (acquire above)
        float acc = partials[tid] + partials[tid + 256];
        #pragma unroll
        for (int off = 32; off > 0; off >>= 1) acc += __shfl_down(acc, off, 64);
        if ((tid & 63) == 0) sR[tid >> 6] = acc;
        __syncthreads();
        if (tid == 0) out[0] = sR[0] + sR[1] + sR[2] + sR[3];
    }
}

extern "C" void kernel_launch(void* const* d_in, const int* in_sizes, int n_in,
                              void* d_out, int out_size, void* d_ws, size_t ws_size,
                              hipStream_t stream) {
    const float* coords = (const float*)d_in[0];   // [4096][3]
    const float* params = (const float*)d_in[1];   // [4096][22]
    float* out = (float*)d_out;

    float* partials = (float*)d_ws;                       // [512]
    int*   done_ctr = (int*)((float*)d_ws + NBLK);        // [1]
    float* packed   = (float*)d_ws + NBLK + 256;          // [4096][12], aligned

    pack_kernel<<<N_ATOMS / 256, 256, 0, stream>>>(coords, params, packed, done_ctr);
    eam_fused_kernel<<<NBLK, 256, 0, stream>>>(params, packed, partials, done_ctr, out);
}

// Round 5
// 39.564 us; speedup vs baseline: 1.0861x; 1.0861x over previous
//
#include <hip/hip_runtime.h>
#include <math.h>

#define N_ATOMS 4096
#define CUTOFF2 25.0f
#define NBLK    512
#define BS      1024                 // threads per block (16 waves)
#define IPB     8                    // i atoms per block; 128 lanes per i
#define CHUNK   256                  // j atoms staged per chunk
#define NCHUNK  (N_ATOMS / CHUNK)    // 16
#define LOG2E   1.4426950408889634f
#define LN2     0.6931471805599453f

__device__ __forceinline__ float pow20f(float t) {
    float t2 = t * t;
    float t4 = t2 * t2;
    float t8 = t4 * t4;
    float t16 = t8 * t8;
    return t16 * t4;
}

// SoA packed params:
//   q0 = {x, y, z, re_inv}
//   q1 = {c1b=beta*log2e, la, fe, Bof=B/fe}   (exp arg = fma(-x, c1b, c1b))
//   q2 = {c1a=alpha*log2e, ka, A, 0}
__global__ __launch_bounds__(256) void pack_kernel(
    const float* __restrict__ coords, const float* __restrict__ params,
    float4* __restrict__ q0g, float4* __restrict__ q1g, float4* __restrict__ q2g,
    int* __restrict__ done_ctr)
{
    if (blockIdx.x == 0 && threadIdx.x == 0) *done_ctr = 0;
    const int a = blockIdx.x * 256 + threadIdx.x;
    const float* p = params + 22 * a;
    const float fe = p[1];
    q0g[a] = { coords[3*a], coords[3*a+1], coords[3*a+2], __builtin_amdgcn_rcpf(p[0]) };
    q1g[a] = { p[5] * LOG2E, p[9], fe, p[7] * __builtin_amdgcn_rcpf(fe) };
    q2g[a] = { p[4] * LOG2E, p[8], p[6], 0.0f };
}

// 512 blocks x 1024 threads (32 waves/CU). Block owns 8 i-atoms; 128 lanes per i.
// Full rho + F(rho) + pair-e in one kernel; last-done block sums 512 partials.
__global__ __launch_bounds__(1024) void eam_fused_kernel(
    const float* __restrict__ params,
    const float4* __restrict__ q0g, const float4* __restrict__ q1g,
    const float4* __restrict__ q2g,
    float* __restrict__ partials, int* __restrict__ done_ctr,
    float* __restrict__ out)
{
    __shared__ float4 sq0[CHUNK], sq1[CHUNK], sq2[CHUNK];   // 12 KB
    __shared__ float sRho[16];
    __shared__ float sE[16];
    __shared__ float sF[IPB];
    __shared__ float sR[16];
    __shared__ int   sLast;

    const int tid     = threadIdx.x;
    const int il      = tid >> 7;       // 0..7: which i
    const int lane128 = tid & 127;
    const int i       = blockIdx.x * IPB + il;

    const float4 pi0 = q0g[i];
    const float4 pi1 = q1g[i];
    const float4 pi2 = q2g[i];
    const float xi = pi0.x, yi = pi0.y, zi = pi0.z, re_inv_i = pi0.w;
    const float c1b_i = pi1.x, la_i = pi1.y, fe_i = pi1.z, Bof_i = pi1.w;
    const float c1a_i = pi2.x, ka_i = pi2.y, A_i = pi2.z;

    float rho = 0.0f;
    float e   = 0.0f;

    for (int c = 0; c < NCHUNK; ++c) {
        __syncthreads();
        if (tid < 256)       sq0[tid]       = q0g[c * CHUNK + tid];
        else if (tid < 512)  sq1[tid - 256] = q1g[c * CHUNK + tid - 256];
        else if (tid < 768)  sq2[tid - 512] = q2g[c * CHUNK + tid - 512];
        __syncthreads();

        #pragma unroll
        for (int k = 0; k < CHUNK / 128; ++k) {
            const int jj = lane128 + 128 * k;
            const int j  = c * CHUNK + jj;
            const float4 q0 = sq0[jj];
            const float4 q1 = sq1[jj];
            const float dx = q0.x - xi;
            const float dy = q0.y - yi;
            const float dz = q0.z - zi;
            const float r2 = fmaf(dx, dx, fmaf(dy, dy, dz * dz));
            const float r  = __builtin_amdgcn_sqrtf(r2);
            const float x  = r * q0.w;
            const float ej = __builtin_amdgcn_exp2f(fmaf(-x, q1.x, q1.x));
            const float dj = __builtin_amdgcn_rcpf(1.0f + pow20f(x - q1.y));
            const float frj = q1.z * ej * dj;
            rho += (j == i) ? 0.0f : frj;

            if (r2 <= CUTOFF2 && i < j) {   // each unordered pair exactly once
                const float4 q2 = sq2[jj];
                const float xr  = r * re_inv_i;
                const float ei  = __builtin_amdgcn_exp2f(fmaf(-xr, c1b_i, c1b_i));
                const float di  = __builtin_amdgcn_rcpf(1.0f + pow20f(xr - la_i));
                const float fri = fe_i * ei * di;
                const float ph_i = A_i * __builtin_amdgcn_exp2f(fmaf(-xr, c1a_i, c1a_i))
                                       * __builtin_amdgcn_rcpf(1.0f + pow20f(xr - ka_i))
                                 - Bof_i * fri;
                const float ph_j = q2.z * __builtin_amdgcn_exp2f(fmaf(-x, q2.x, q2.x))
                                        * __builtin_amdgcn_rcpf(1.0f + pow20f(x - q2.y))
                                 - q1.w * frj;
                // frj/fri*ph_i + fri/frj*ph_j = (frj^2*ph_i + fri^2*ph_j)/(fri*frj)
                e += 0.5f * fmaf(frj * frj, ph_i, fri * fri * ph_j)
                          * __builtin_amdgcn_rcpf(fri * frj);
            }
        }
    }

    // per-wave reductions (wave = 64 lanes; i-group = 2 waves)
    #pragma unroll
    for (int off = 32; off > 0; off >>= 1) {
        rho += __shfl_down(rho, off, 64);
        e   += __shfl_down(e,   off, 64);
    }
    const int wid = tid >> 6;   // 0..15
    if ((tid & 63) == 0) { sRho[wid] = rho; sE[wid] = e; }
    __syncthreads();

    if (tid < IPB) {   // embedding F(rho) for i-atom tid
        const float rhoi = sRho[2 * tid] + sRho[2 * tid + 1];
        const float* p = params + 22 * (blockIdx.x * IPB + tid);
        float F;
        if (rhoi < p[20]) {
            const float xn = rhoi / p[20] - 1.0f;
            F = p[10] + xn * (p[11] + xn * (p[12] + xn * p[13]));
        } else if (rhoi < p[21]) {
            const float xe = rhoi / p[2] - 1.0f;
            F = p[14] + xe * (p[15] + xe * (p[16] + xe * p[17]));
        } else {
            const float l2 = __builtin_amdgcn_logf(rhoi / p[3]);   // log2
            const float t  = __builtin_amdgcn_exp2f(p[18] * l2);
            const float lt = p[18] * l2 * LN2;
            F = p[19] * (1.0f - lt) * t;
        }
        sF[tid] = F;
    }
    __syncthreads();

    if (tid == 0) {
        float part = 0.0f;
        #pragma unroll
        for (int k = 0; k < 16; ++k) part += sE[k];
        #pragma unroll
        for (int k = 0; k < IPB; ++k) part += sF[k];
        partials[blockIdx.x] = part;
        int prev = __hip_atomic_fetch_add(done_ctr, 1, __ATOMIC_ACQ_REL,
                                          __HIP_MEMORY_SCOPE_AGENT);
        sLast = (prev == NBLK - 1);
    }
    __syncthreads();

    if (sLast) {   // last-arriving block: all partials visible
        float acc = (tid < NBLK) ? partials[tid] : 0.0f;
        #pragma unroll
        for (int off = 32; off > 0; off >>= 1) acc += __shfl_down(acc, off, 64);
        if ((tid & 63) == 0) sR[tid >> 6] = acc;
        __syncthreads();
        if (tid == 0) {
            float s = 0.0f;
            #pragma unroll
            for (int k = 0; k < 16; ++k) s += sR[k];
            out[0] = s;
        }
    }
}

extern "C" void kernel_launch(void* const* d_in, const int* in_sizes, int n_in,
                              void* d_out, int out_size, void* d_ws, size_t ws_size,
                              hipStream_t stream) {
    const float* coords = (const float*)d_in[0];   // [4096][3]
    const float* params = (const float*)d_in[1];   // [4096][22]
    float* out = (float*)d_out;

    float* partials = (float*)d_ws;                           // [512]
    int*   done_ctr = (int*)((float*)d_ws + NBLK);            // [1]
    float4* q0g = (float4*)((float*)d_ws + NBLK + 256);       // [4096]
    float4* q1g = q0g + N_ATOMS;
    float4* q2g = q1g + N_ATOMS;

    pack_kernel<<<N_ATOMS / 256, 256, 0, stream>>>(coords, params, q0g, q1g, q2g, done_ctr);
    eam_fused_kernel<<<NBLK, BS, 0, stream>>>(params, q0g, q1g, q2g, partials, done_ctr, out);
}